// Round 9
// baseline (165.606 us; speedup 1.0000x reference)
//
#include <hip/hip_runtime.h>

#define DIM     1024
#define BATCH   512
#define OUTD    5377
#define NHEADS  10
#define NLAYERS 5
#define LDK     72   // padded bf16 leading dim for MLP tiles

typedef __attribute__((ext_vector_type(4))) float f32x4;
typedef __attribute__((ext_vector_type(8))) short bf16x8;

__device__ __forceinline__ unsigned short f2bf(float f) {
    unsigned u = __builtin_bit_cast(unsigned, f);
    u = (u + 0x7FFFu + ((u >> 16) & 1u)) >> 16;
    return (unsigned short)u;
}
__device__ __forceinline__ float bf2f(unsigned short h) {
    unsigned u = ((unsigned)h) << 16;
    return __builtin_bit_cast(float, u);
}
__device__ __forceinline__ unsigned pk2(float a, float b) {
    return (unsigned)f2bf(a) | ((unsigned)f2bf(b) << 16);
}

// ---------------- grouping: bucket batches by rule_len ----------------
__global__ void group_kernel(const int* __restrict__ rule_len,
                             int* __restrict__ bidx,
                             int* __restrict__ gstart,
                             int* __restrict__ gcount) {
    __shared__ int s_count[NHEADS];
    __shared__ int s_fill[NHEADS];
    int t = threadIdx.x;
    if (t < NHEADS) s_count[t] = 0;
    __syncthreads();
    int h = rule_len[t];
    atomicAdd(&s_count[h], 1);
    __syncthreads();
    if (t == 0) {
        int acc = 0;
        for (int i = 0; i < NHEADS; ++i) {
            gstart[i] = acc;
            gcount[i] = s_count[i];
            s_fill[i] = acc;
            acc += s_count[i];
        }
    }
    __syncthreads();
    int pos = atomicAdd(&s_fill[h], 1);
    bidx[pos] = t;
}

// ---------------- latent f32 -> bf16 ----------------
__global__ void convert_latent(const float* __restrict__ in,
                               unsigned short* __restrict__ out) {
    int i = blockIdx.x * blockDim.x + threadIdx.x;   // one float4 per thread
    float4 v = ((const float4*)in)[i];
    ushort4 o;
    o.x = f2bf(v.x); o.y = f2bf(v.y); o.z = f2bf(v.z); o.w = f2bf(v.w);
    ((ushort4*)out)[i] = o;
}

// ---------------- W_mlp f32 -> (hi,lo) bf16, once ----------------
__global__ void cvt_wmlp(const float* __restrict__ W,
                         unsigned short* __restrict__ hi,
                         unsigned short* __restrict__ lo) {
    size_t i = ((size_t)blockIdx.x * blockDim.x + threadIdx.x) * 4;
    float4 v = *(const float4*)(W + i);
    ushort4 h, l;
    h.x = f2bf(v.x); l.x = f2bf(v.x - bf2f(h.x));
    h.y = f2bf(v.y); l.y = f2bf(v.y - bf2f(h.y));
    h.z = f2bf(v.z); l.z = f2bf(v.z - bf2f(h.z));
    h.w = f2bf(v.w); l.w = f2bf(v.w - bf2f(h.w));
    *(ushort4*)(hi + i) = h;
    *(ushort4*)(lo + i) = l;
}

// -------- MLP layer: C = A @ W^T + bias (MFMA, pre-converted hi/lo W) --------
__global__ __launch_bounds__(256) void mlp_mfma(
    const unsigned short* __restrict__ A,
    const unsigned short* __restrict__ WhiG,   // DIM x DIM bf16 (hi)
    const unsigned short* __restrict__ WloG,   // DIM x DIM bf16 (lo)
    const float* __restrict__ bias,
    unsigned short* __restrict__ C)
{
    __shared__ __align__(16) unsigned short As[2][32][LDK];
    __shared__ __align__(16) unsigned short Whi[2][32][LDK];
    __shared__ __align__(16) unsigned short Wlo[2][32][LDK];

    const int tid = threadIdx.x;
    const int n0 = blockIdx.x * 32;
    const int m0 = blockIdx.y * 32;
    const int lane = tid & 63;
    const int wid = tid >> 6;
    const int wm = (wid >> 1) * 16;
    const int wn = (wid & 1) * 16;

    f32x4 acc = {0.f, 0.f, 0.f, 0.f};

    const int sr = tid >> 3;          // 0..31  (A row and W row)
    const int sc = (tid & 7) * 8;     // 0..56  bf16 units

    const unsigned short* Ap = A    + (size_t)(m0 + sr) * DIM + sc;
    const unsigned short* Hp = WhiG + (size_t)(n0 + sr) * DIM + sc;
    const unsigned short* Lp = WloG + (size_t)(n0 + sr) * DIM + sc;

    uint4 ra = *(const uint4*)(Ap);
    uint4 rh = *(const uint4*)(Hp);
    uint4 rl = *(const uint4*)(Lp);

    for (int t = 0; t < DIM / 64; ++t) {
        const int cur = t & 1;
        *(uint4*)&As[cur][sr][sc]  = ra;
        *(uint4*)&Whi[cur][sr][sc] = rh;
        *(uint4*)&Wlo[cur][sr][sc] = rl;
        __syncthreads();
        if (t < DIM / 64 - 1) {
            const int k0 = (t + 1) * 64;
            ra = *(const uint4*)(Ap + k0);
            rh = *(const uint4*)(Hp + k0);
            rl = *(const uint4*)(Lp + k0);
        }
        #pragma unroll
        for (int kk = 0; kk < 2; ++kk) {
            const int ko = kk * 32 + (lane >> 4) * 8;
            bf16x8 a  = *(const bf16x8*)&As[cur][wm + (lane & 15)][ko];
            bf16x8 bh = *(const bf16x8*)&Whi[cur][wn + (lane & 15)][ko];
            bf16x8 bl = *(const bf16x8*)&Wlo[cur][wn + (lane & 15)][ko];
            acc = __builtin_amdgcn_mfma_f32_16x16x32_bf16(a, bh, acc, 0, 0, 0);
            acc = __builtin_amdgcn_mfma_f32_16x16x32_bf16(a, bl, acc, 0, 0, 0);
        }
        __syncthreads();
    }

    const int cn = n0 + wn + (lane & 15);
    const float bn = bias[cn];
    const int rbase = m0 + wm + (lane >> 4) * 4;
    #pragma unroll
    for (int j = 0; j < 4; ++j) {
        C[(size_t)(rbase + j) * DIM + cn] = f2bf(acc[j] + bn);
    }
}

// ------- head "rowband": 256-f32 K-chunks, per-thread 256B-contiguous W reads -
// Block: 4 waves, tile 64m x 64n, K=1024 in 4 chunks of 256.
// W chunk (64 rows x 1KB f32) -> regs (contiguous per thread) -> packed bf16
// into a single 32KB LDS buffer with XOR-swizzled 16B granules (2-way = free).
// A fragments gathered direct-to-reg from L2-hot H. 8 barriers total.
#define SWZ(r) ((((r) & 7) << 2) | (((r) >> 3) & 3))

__global__ __launch_bounds__(256) void head_rb(
    const unsigned short* __restrict__ H,   // BATCH x DIM bf16
    const float* __restrict__ Wh,           // NHEADS x OUTD x DIM f32
    const float* __restrict__ bh,           // NHEADS x OUTD f32
    const int* __restrict__ bidx,
    const int* __restrict__ gstart,
    const int* __restrict__ gcount,
    float* __restrict__ out)                // BATCH x OUTD f32
{
    const int head = blockIdx.z;
    const int cnt  = gcount[head];
    const int m0   = blockIdx.y * 64;
    if (m0 >= cnt) return;
    const int start = gstart[head];
    const int n0 = blockIdx.x * 64;

    __shared__ __align__(16) unsigned short Wt[64][256];  // 32 KB, swizzled granules

    const int tid  = threadIdx.x;
    const int lane = tid & 63;
    const int wv   = tid >> 6;
    const int col  = lane & 15;
    const int hk   = lane >> 4;

    // W stage: thread -> row sr = tid&63, k-part = tid>>6 (256 B contiguous)
    const int sr   = tid & 63;
    const int part = tid >> 6;
    int srow = n0 + sr; if (srow > OUTD - 1) srow = OUTD - 1;
    const float* wsrc = Wh + (size_t)head * OUTD * DIM + (size_t)srow * DIM + part * 64;

    // A fragment bases: lane's A row = m0 + mf*16 + col (clamped), k-byte off hk*16
    const char* Abp[4];
    #pragma unroll
    for (int mf = 0; mf < 4; ++mf) {
        int m = m0 + mf * 16 + col; if (m > cnt - 1) m = cnt - 1;
        Abp[mf] = (const char*)(H + (size_t)bidx[start + m] * DIM) + hk * 16;
    }

    const int nr = wv * 16 + col;       // LDS W row this lane consumes

    float4 wreg[16];                    // next-chunk prefetch (64 f32 contiguous)
    #pragma unroll
    for (int i = 0; i < 16; ++i) wreg[i] = *(const float4*)(wsrc + i * 4);

    f32x4 acc[4] = {};
    char* lds = (char*)&Wt[0][0];

    #pragma unroll
    for (int c = 0; c < 4; ++c) {
        __syncthreads();   // WAR: previous chunk's reads retired (no-op at c=0)
        #pragma unroll
        for (int j = 0; j < 8; ++j) {   // granule j = f32 [8j..8j+8) of this thread
            float4 r0 = wreg[2 * j], r1 = wreg[2 * j + 1];
            uint4 wk4;
            wk4.x = pk2(r0.x, r0.y); wk4.y = pk2(r0.z, r0.w);
            wk4.z = pk2(r1.x, r1.y); wk4.w = pk2(r1.z, r1.w);
            int g = part * 8 + j;                       // granule index in row (0..31)
            *(uint4*)(lds + sr * 512 + ((g ^ SWZ(sr)) << 4)) = wk4;
        }
        __syncthreads();   // RAW: chunk c visible
        if (c < 3) {
            #pragma unroll
            for (int i = 0; i < 16; ++i)
                wreg[i] = *(const float4*)(wsrc + (c + 1) * 256 + i * 4);
        }
        // compute chunk c: 4 sub-steps of 64 k
        #pragma unroll
        for (int s = 0; s < 4; ++s) {
            uint4 pa[4][2];
            #pragma unroll
            for (int mf = 0; mf < 4; ++mf) {
                #pragma unroll
                for (int kk = 0; kk < 2; ++kk)
                    pa[mf][kk] = *(const uint4*)(Abp[mf] + (c * 4 + s) * 128 + kk * 64);
            }
            #pragma unroll
            for (int kk = 0; kk < 2; ++kk) {
                int g = s * 8 + kk * 4 + hk;
                bf16x8 wf = *(const bf16x8*)(lds + nr * 512 + ((g ^ SWZ(nr)) << 4));
                #pragma unroll
                for (int mf = 0; mf < 4; ++mf) {
                    bf16x8 a = __builtin_bit_cast(bf16x8, pa[mf][kk]);
                    acc[mf] = __builtin_amdgcn_mfma_f32_16x16x32_bf16(a, wf, acc[mf], 0, 0, 0);
                }
            }
        }
    }

    const int n = n0 + nr;
    if (n < OUTD) {
        const float bn = bh[(size_t)head * OUTD + n];
        #pragma unroll
        for (int mf = 0; mf < 4; ++mf) {
            #pragma unroll
            for (int j = 0; j < 4; ++j) {
                int row = m0 + mf * 16 + hk * 4 + j;
                if (row < cnt) {
                    out[(size_t)bidx[start + row] * OUTD + n] = acc[mf][j] + bn;
                }
            }
        }
    }
}

extern "C" void kernel_launch(void* const* d_in, const int* in_sizes, int n_in,
                              void* d_out, int out_size, void* d_ws, size_t ws_size,
                              hipStream_t stream) {
    const float* latent   = (const float*)d_in[0];
    const float* W_mlp    = (const float*)d_in[1];
    const float* b_mlp    = (const float*)d_in[2];
    const float* W_heads  = (const float*)d_in[3];
    const float* b_heads  = (const float*)d_in[4];
    const int*   rule_len = (const int*)d_in[5];
    float* out = (float*)d_out;

    unsigned short* h0  = (unsigned short*)d_ws;
    unsigned short* h1  = h0  + (size_t)BATCH * DIM;
    unsigned short* whi = h1  + (size_t)BATCH * DIM;
    unsigned short* wlo = whi + (size_t)NLAYERS * DIM * DIM;
    int* bidx   = (int*)(wlo + (size_t)NLAYERS * DIM * DIM);
    int* gstart = bidx + BATCH;
    int* gcount = gstart + 16;

    group_kernel<<<1, BATCH, 0, stream>>>(rule_len, bidx, gstart, gcount);
    convert_latent<<<(BATCH * DIM / 4) / 256, 256, 0, stream>>>(latent, h0);
    cvt_wmlp<<<(NLAYERS * DIM * DIM / 4) / 256, 256, 0, stream>>>(W_mlp, whi, wlo);

    dim3 mgrid(DIM / 32, BATCH / 32);
    const unsigned short* src = h0;
    unsigned short* dst = h1;
    for (int l = 0; l < NLAYERS; ++l) {
        mlp_mfma<<<mgrid, 256, 0, stream>>>(src,
                                            whi + (size_t)l * DIM * DIM,
                                            wlo + (size_t)l * DIM * DIM,
                                            b_mlp + (size_t)l * DIM,
                                            dst);
        unsigned short* t = (unsigned short*)src;
        src = dst;
        dst = t;
    }

    dim3 hgrid((OUTD + 63) / 64, 2, NHEADS);
    head_rb<<<hgrid, 256, 0, stream>>>(src, W_heads, b_heads,
                                       bidx, gstart, gcount, out);
}